// Round 2
// baseline (638.555 us; speedup 1.0000x reference)
//
#include <hip/hip_runtime.h>

typedef __bf16 bf16_t;
typedef bf16_t bf16x8 __attribute__((ext_vector_type(8)));
typedef bf16_t bf16x4 __attribute__((ext_vector_type(4)));
typedef float f32x4v __attribute__((ext_vector_type(4)));

// ---------------------------------------------------------------- convert f32 -> bf16
__global__ __launch_bounds__(256) void cvt_k(const float* __restrict__ in,
                                             bf16_t* __restrict__ out, int n4) {
    int i = blockIdx.x * blockDim.x + threadIdx.x;
    if (i >= n4) return;
    float4 v = reinterpret_cast<const float4*>(in)[i];
    bf16x4 o;
    o[0] = (bf16_t)v.x; o[1] = (bf16_t)v.y; o[2] = (bf16_t)v.z; o[3] = (bf16_t)v.w;
    reinterpret_cast<bf16x4*>(out)[i] = o;
}

// ---------------------------------------------------------------- GEMM: C = A @ B^T + bias
// A: [M,K] bf16 row-major with batch row remap; B: [N,K] bf16 row-major.
// EPI: 0 = store bf16, 1 = gelu->bf16, 2 = newx += gate*(v), 3 = store f32
template <int EPI>
__global__ __launch_bounds__(256) void gemm_bt(
    const bf16_t* __restrict__ A, int aBatchStride, int aRowOff, int lda,
    const bf16_t* __restrict__ Bw, int ldb,
    const float* __restrict__ bias,
    void* __restrict__ Out, int ldo, int outColOff,
    const float* __restrict__ gate, int gidx,
    int M, int N, int K) {
    __shared__ __attribute__((aligned(16))) bf16_t As[64][40];
    __shared__ __attribute__((aligned(16))) bf16_t Bs[64][40];
    const int tid = threadIdx.x;
    const int lane = tid & 63;
    const int wv = tid >> 6;
    const int wm = wv >> 1, wn = wv & 1;
    const int tm = blockIdx.y, tn = blockIdx.x;
    const int l15 = lane & 15, l16 = lane >> 4;

    const int lrow = tid >> 2;       // 0..63
    const int lcol = (tid & 3) * 8;  // 0,8,16,24

    int am = tm * 64 + lrow;
    int agrow = (am >> 10) * aBatchStride + aRowOff + (am & 1023);
    const bf16_t* aptr = A + (size_t)agrow * lda + lcol;
    const bf16_t* bptr = Bw + (size_t)(tn * 64 + lrow) * ldb + lcol;

    f32x4v acc[2][2] = {};

    for (int k0 = 0; k0 < K; k0 += 32) {
        bf16x8 av = *reinterpret_cast<const bf16x8*>(aptr + k0);
        bf16x8 bv = *reinterpret_cast<const bf16x8*>(bptr + k0);
        __syncthreads();
        *reinterpret_cast<bf16x8*>(&As[lrow][lcol]) = av;
        *reinterpret_cast<bf16x8*>(&Bs[lrow][lcol]) = bv;
        __syncthreads();
        bf16x8 af[2], bff[2];
#pragma unroll
        for (int i = 0; i < 2; ++i) {
            af[i]  = *reinterpret_cast<const bf16x8*>(&As[wm * 32 + i * 16 + l15][l16 * 8]);
            bff[i] = *reinterpret_cast<const bf16x8*>(&Bs[wn * 32 + i * 16 + l15][l16 * 8]);
        }
#pragma unroll
        for (int mi = 0; mi < 2; ++mi)
#pragma unroll
            for (int ni = 0; ni < 2; ++ni)
                acc[mi][ni] = __builtin_amdgcn_mfma_f32_16x16x32_bf16(af[mi], bff[ni], acc[mi][ni], 0, 0, 0);
    }

#pragma unroll
    for (int mi = 0; mi < 2; ++mi) {
#pragma unroll
        for (int ni = 0; ni < 2; ++ni) {
#pragma unroll
            for (int i = 0; i < 4; ++i) {
                int row = tm * 64 + wm * 32 + mi * 16 + l16 * 4 + i;
                int col = tn * 64 + wn * 32 + ni * 16 + l15;
                float v = acc[mi][ni][i] + bias[col];
                if constexpr (EPI == 0) {
                    ((bf16_t*)Out)[(size_t)row * ldo + outColOff + col] = (bf16_t)v;
                } else if constexpr (EPI == 1) {
                    float g = 0.5f * v * (1.0f + erff(v * 0.70710678118654752f));
                    ((bf16_t*)Out)[(size_t)row * ldo + outColOff + col] = (bf16_t)g;
                } else if constexpr (EPI == 2) {
                    ((float*)Out)[(size_t)row * ldo + col] += gate[row * 5 + gidx] * v;
                } else {
                    ((float*)Out)[(size_t)row * ldo + col] = v;
                }
            }
        }
    }
}

// ---------------------------------------------------------------- attention
// qkv: [4096][1536] bf16 (cols 0..511 Q, 512..1023 K, 1024..1535 V, head-major 64 each)
// MASK: 0 none, 1 rev (keep inside band), 2 fwd (exclude inside band)
template <int MASK>
__global__ __launch_bounds__(256) void attn_k(const bf16_t* __restrict__ qkv,
                                              bf16_t* __restrict__ outp) {
    __shared__ __attribute__((aligned(16))) bf16_t Ps[4][16][40];
    const int tid = threadIdx.x;
    const int lane = tid & 63;
    const int w = tid >> 6;
    const int qt = blockIdx.x, h = blockIdx.y, b = blockIdx.z;
    const int l15 = lane & 15, l16 = lane >> 4;

    const int qr = qt * 64 + w * 16;   // local q row base (0..1023)
    const int qrow = b * 1024 + qr;    // global token row base
    const int qblk = qr >> 5;

    bf16x8 aq[2];
#pragma unroll
    for (int s = 0; s < 2; ++s)
        aq[s] = *reinterpret_cast<const bf16x8*>(
            qkv + (size_t)(qrow + l15) * 1536 + h * 64 + s * 32 + l16 * 8);

    float mrow[4], lsum[4];
    f32x4v accO[4] = {};
#pragma unroll
    for (int i = 0; i < 4; ++i) { mrow[i] = -1e30f; lsum[i] = 0.f; }

    for (int kt = 0; kt < 32; ++kt) {
        int bd = qblk - kt; if (bd < 0) bd = -bd;
        if (MASK == 1 && bd > 3) continue;
        const bool needMask = (MASK == 1) || (MASK == 2 && bd <= 3);

        const bf16_t* kbase = qkv + (size_t)(b * 1024 + kt * 32) * 1536 + 512 + h * 64;
        f32x4v sc[2];
#pragma unroll
        for (int n = 0; n < 2; ++n) {
            bf16x8 bk0 = *reinterpret_cast<const bf16x8*>(kbase + (size_t)(n * 16 + l15) * 1536 + l16 * 8);
            bf16x8 bk1 = *reinterpret_cast<const bf16x8*>(kbase + (size_t)(n * 16 + l15) * 1536 + 32 + l16 * 8);
            f32x4v z = {};
            z = __builtin_amdgcn_mfma_f32_16x16x32_bf16(aq[0], bk0, z, 0, 0, 0);
            sc[n] = __builtin_amdgcn_mfma_f32_16x16x32_bf16(aq[1], bk1, z, 0, 0, 0);
        }

        float pv[2][4];
#pragma unroll
        for (int n = 0; n < 2; ++n)
#pragma unroll
            for (int i = 0; i < 4; ++i) {
                float v = sc[n][i] * 0.125f;
                if (needMask) {
                    int q = qr + l16 * 4 + i;
                    int k = kt * 32 + n * 16 + l15;
                    int dq = (q & 31) - (k & 31); if (dq < 0) dq = -dq;
                    bool inside = (bd <= 3) && (dq <= 3);
                    bool kill = (MASK == 1) ? (!inside) : inside;
                    if (kill) v = -1e30f;
                }
                pv[n][i] = v;
            }

        float fac[4];
#pragma unroll
        for (int i = 0; i < 4; ++i) {
            float tmx = fmaxf(pv[0][i], pv[1][i]);
#pragma unroll
            for (int d = 1; d <= 8; d <<= 1) tmx = fmaxf(tmx, __shfl_xor(tmx, d, 64));
            float mn = fmaxf(mrow[i], tmx);
            fac[i] = __expf(mrow[i] - mn);
            mrow[i] = mn;
            float p0 = __expf(pv[0][i] - mn);
            float p1 = __expf(pv[1][i] - mn);
            pv[0][i] = p0; pv[1][i] = p1;
            float rs = p0 + p1;
#pragma unroll
            for (int d = 1; d <= 8; d <<= 1) rs += __shfl_xor(rs, d, 64);
            lsum[i] = lsum[i] * fac[i] + rs;
        }
#pragma unroll
        for (int dblk = 0; dblk < 4; ++dblk)
#pragma unroll
            for (int i = 0; i < 4; ++i) accO[dblk][i] *= fac[i];

        // P tile -> LDS (wave-private), reread in A-frag layout
#pragma unroll
        for (int n = 0; n < 2; ++n)
#pragma unroll
            for (int i = 0; i < 4; ++i)
                Ps[w][l16 * 4 + i][n * 16 + l15] = (bf16_t)pv[n][i];
        bf16x8 pa = *reinterpret_cast<const bf16x8*>(&Ps[w][l15][l16 * 8]);

        const bf16_t* vbase = qkv + (size_t)(b * 1024 + kt * 32) * 1536 + 1024 + h * 64;
#pragma unroll
        for (int dblk = 0; dblk < 4; ++dblk) {
            bf16x8 bv;
#pragma unroll
            for (int j = 0; j < 8; ++j)
                bv[j] = vbase[(size_t)(l16 * 8 + j) * 1536 + dblk * 16 + l15];
            accO[dblk] = __builtin_amdgcn_mfma_f32_16x16x32_bf16(pa, bv, accO[dblk], 0, 0, 0);
        }
    }

    float inv[4];
#pragma unroll
    for (int i = 0; i < 4; ++i) inv[i] = 1.0f / lsum[i];
#pragma unroll
    for (int dblk = 0; dblk < 4; ++dblk)
#pragma unroll
        for (int i = 0; i < 4; ++i)
            outp[(size_t)(qrow + l16 * 4 + i) * 512 + h * 64 + dblk * 16 + l15] =
                (bf16_t)(accO[dblk][i] * inv[i]);
}

// ---------------------------------------------------------------- LayerNorm (D=512)
__global__ __launch_bounds__(256) void ln_k(const float* __restrict__ in0,
                                            const float* __restrict__ in1,
                                            const float* __restrict__ g,
                                            const float* __restrict__ bb,
                                            float* __restrict__ outf,
                                            bf16_t* __restrict__ outb) {
    __shared__ float red[8];
    int row = blockIdx.x;
    int t = threadIdx.x;
    float x0 = in0[(size_t)row * 512 + t];
    float x1 = in0[(size_t)row * 512 + 256 + t];
    if (in1) {
        x0 += in1[(size_t)row * 512 + t];
        x1 += in1[(size_t)row * 512 + 256 + t];
    }
    float s = x0 + x1, sq = x0 * x0 + x1 * x1;
#pragma unroll
    for (int d = 1; d < 64; d <<= 1) {
        s += __shfl_xor(s, d, 64);
        sq += __shfl_xor(sq, d, 64);
    }
    int w = t >> 6;
    if ((t & 63) == 0) { red[w] = s; red[4 + w] = sq; }
    __syncthreads();
    s = red[0] + red[1] + red[2] + red[3];
    sq = red[4] + red[5] + red[6] + red[7];
    float mean = s * (1.0f / 512.0f);
    float var = sq * (1.0f / 512.0f) - mean * mean;
    float rstd = rsqrtf(var + 1e-5f);
    float y0 = (x0 - mean) * rstd * g[t] + bb[t];
    float y1 = (x1 - mean) * rstd * g[256 + t] + bb[256 + t];
    if (outf) {
        outf[(size_t)row * 512 + t] = y0;
        outf[(size_t)row * 512 + 256 + t] = y1;
    }
    if (outb) {
        outb[(size_t)row * 512 + t] = (bf16_t)y0;
        outb[(size_t)row * 512 + 256 + t] = (bf16_t)y1;
    }
}

// ----------------------------------------------------------------
extern "C" void kernel_launch(void* const* d_in, const int* in_sizes, int n_in,
                              void* d_out, int out_size, void* d_ws, size_t ws_size,
                              hipStream_t stream) {
    (void)in_sizes; (void)n_in; (void)out_size; (void)ws_size;
    const float* x       = (const float*)d_in[0];
    const float* ref_mca = (const float*)d_in[1];
    const float* gate    = (const float*)d_in[2];
    const float *w[5], *wb_bias[5], *ow[5], *ob[5];
    for (int p = 0; p < 5; ++p) {
        w[p]       = (const float*)d_in[3 + p * 4];
        wb_bias[p] = (const float*)d_in[4 + p * 4];
        ow[p]      = (const float*)d_in[5 + p * 4];
        ob[p]      = (const float*)d_in[6 + p * 4];
    }
    const float* ln1_g = (const float*)d_in[23];
    const float* ln1_b = (const float*)d_in[24];
    const float* ln2_g = (const float*)d_in[25];
    const float* ln2_b = (const float*)d_in[26];
    const float* fc1_w = (const float*)d_in[27];
    const float* fc1_b = (const float*)d_in[28];
    const float* fc2_w = (const float*)d_in[29];
    const float* fc2_b = (const float*)d_in[30];

    char* ws = (char*)d_ws;
    size_t off = 0;
    auto alloc = [&](size_t bytes) {
        char* p = ws + off;
        off += (bytes + 255) & ~(size_t)255;
        return p;
    };
    bf16_t* xb   = (bf16_t*)alloc((size_t)4096 * 512 * 2);
    bf16_t* refb = (bf16_t*)alloc((size_t)8192 * 512 * 2);
    bf16_t *wbv[5], *owb[5];
    for (int p = 0; p < 5; ++p) {
        wbv[p] = (bf16_t*)alloc((size_t)1536 * 512 * 2);
        owb[p] = (bf16_t*)alloc((size_t)512 * 512 * 2);
    }
    bf16_t* qkvb = (bf16_t*)alloc((size_t)4096 * 1536 * 2);
    bf16_t* attnout = (bf16_t*)alloc((size_t)4096 * 512 * 2);  // contiguous after qkvb
    bf16_t* ub = qkvb;  // [4096,2048] aliases qkvb+attnout (16.78 MB), dead by MLP time
    float* newx = (float*)alloc((size_t)4096 * 512 * 4);
    float* hbuf = (float*)alloc((size_t)4096 * 512 * 4);
    // aliases over dead-by-then regions:
    bf16_t* hb   = refb;       // [4096,512] bf16; refb dead after nsa K-proj
    bf16_t* fc1b = wbv[0];     // [2048,512] bf16 = 2.1MB = wbv[0]+owb[0]; dead after oproj(4)
    bf16_t* fc2b = wbv[1];     // [512,2048] bf16 = 2.1MB = wbv[1]+owb[1]
    float* ybuf = newx;        // reuse: newx consumed by LN1 before G2 writes y

    hipMemsetAsync(newx, 0, (size_t)4096 * 512 * 4, stream);

    auto cvt = [&](const float* src, bf16_t* dst, int n) {
        int n4 = n / 4;
        cvt_k<<<(n4 + 255) / 256, 256, 0, stream>>>(src, dst, n4);
    };
    cvt(x, xb, 4096 * 512);
    cvt(ref_mca, refb, 8192 * 512);
    for (int p = 0; p < 5; ++p) {
        cvt(w[p], wbv[p], 1536 * 512);
        cvt(ow[p], owb[p], 512 * 512);
    }

    dim3 blk(256);
    auto proj = [&](const bf16_t* A, int abs_, int aro, const bf16_t* Wrow,
                    const float* brow, int N, int colOff) {
        dim3 g(N / 64, 64);
        gemm_bt<0><<<g, blk, 0, stream>>>(A, abs_, aro, 512, Wrow, 512, brow,
                                          qkvb, 1536, colOff, nullptr, 0, 4096, N, 512);
    };
    auto attn = [&](int mask) {
        dim3 g(16, 8, 4);
        if (mask == 0)      attn_k<0><<<g, blk, 0, stream>>>(qkvb, attnout);
        else if (mask == 1) attn_k<1><<<g, blk, 0, stream>>>(qkvb, attnout);
        else                attn_k<2><<<g, blk, 0, stream>>>(qkvb, attnout);
    };
    auto oproj = [&](int p, int gidx) {
        dim3 g(512 / 64, 64);
        gemm_bt<2><<<g, blk, 0, stream>>>(attnout, 1024, 0, 512, owb[p], 512, ob[p],
                                          newx, 512, 0, gate, gidx, 4096, 512, 512);
    };

    // mca: q from x (once); k,v from each ref chunk; rev mask; gate 0
    proj(xb, 1024, 0, wbv[0], wb_bias[0], 512, 0);
    for (int r = 0; r < 2; ++r) {
        proj(refb, 2048, r * 1024, wbv[0] + (size_t)512 * 512, wb_bias[0] + 512, 1024, 512);
        attn(1);
        oproj(0, 0);
    }
    // ca: q from x; k,v from ref_last; no mask; gate 1
    proj(xb, 1024, 0, wbv[1], wb_bias[1], 512, 0);
    proj(refb, 2048, 1024, wbv[1] + (size_t)512 * 512, wb_bias[1] + 512, 1024, 512);
    attn(0);
    oproj(1, 1);
    // msa: all from x; fwd mask; gate 2
    proj(xb, 1024, 0, wbv[2], wb_bias[2], 1536, 0);
    attn(2);
    oproj(2, 2);
    // nsa: q,v from x; k from ref_last; fwd mask; gate 3
    proj(xb, 1024, 0, wbv[3], wb_bias[3], 512, 0);
    proj(refb, 2048, 1024, wbv[3] + (size_t)512 * 512, wb_bias[3] + 512, 512, 512);
    proj(xb, 1024, 0, wbv[3] + (size_t)1024 * 512, wb_bias[3] + 1024, 512, 1024);
    attn(2);
    oproj(3, 3);
    // sa: all from x; no mask; gate 4
    proj(xb, 1024, 0, wbv[4], wb_bias[4], 1536, 0);
    attn(0);
    oproj(4, 4);

    // weight buffers for MLP now free; convert fc1/fc2 into aliased space
    cvt(fc1_w, fc1b, 2048 * 512);
    cvt(fc2_w, fc2b, 512 * 2048);

    // LN1 -> h (f32 + bf16); hb aliases refb (dead now)
    ln_k<<<4096, blk, 0, stream>>>(newx, nullptr, ln1_g, ln1_b, hbuf, hb);
    // G1: gelu(h @ fc1^T + b1) -> ub  [4096,2048] bf16
    {
        dim3 g(2048 / 64, 64);
        gemm_bt<1><<<g, blk, 0, stream>>>(hb, 1024, 0, 512, fc1b, 512, fc1_b,
                                          ub, 2048, 0, nullptr, 0, 4096, 2048, 512);
    }
    // G2: ub @ fc2^T + b2 -> y (f32)
    {
        dim3 g(512 / 64, 64);
        gemm_bt<3><<<g, blk, 0, stream>>>(ub, 1024, 0, 2048, fc2b, 2048, fc2_b,
                                          ybuf, 512, 0, nullptr, 0, 4096, 512, 2048);
    }
    // LN2(h + y) -> out: FLOAT32 (reference output dtype is f32)
    ln_k<<<4096, blk, 0, stream>>>(hbuf, ybuf, ln2_g, ln2_b, (float*)d_out, nullptr);
}

// Round 3
// 477.392 us; speedup vs baseline: 1.3376x; 1.3376x over previous
//
#include <hip/hip_runtime.h>

typedef __bf16 bf16_t;
typedef bf16_t bf16x8 __attribute__((ext_vector_type(8)));
typedef bf16_t bf16x4 __attribute__((ext_vector_type(4)));
typedef float f32x4v __attribute__((ext_vector_type(4)));

// ---------------------------------------------------------------- convert f32 -> bf16
__global__ __launch_bounds__(256) void cvt_k(const float* __restrict__ in,
                                             bf16_t* __restrict__ out, int n4) {
    int i = blockIdx.x * blockDim.x + threadIdx.x;
    if (i >= n4) return;
    float4 v = reinterpret_cast<const float4*>(in)[i];
    bf16x4 o;
    o[0] = (bf16_t)v.x; o[1] = (bf16_t)v.y; o[2] = (bf16_t)v.z; o[3] = (bf16_t)v.w;
    reinterpret_cast<bf16x4*>(out)[i] = o;
}

// ---------------------------------------------------------------- GEMM: C = A @ B^T + bias
template <int EPI>
__global__ __launch_bounds__(256) void gemm_bt(
    const bf16_t* __restrict__ A, int aBatchStride, int aRowOff, int lda,
    const bf16_t* __restrict__ Bw, int ldb,
    const float* __restrict__ bias,
    void* __restrict__ Out, int ldo, int outColOff,
    const float* __restrict__ gate, int gidx,
    int M, int N, int K) {
    __shared__ __attribute__((aligned(16))) bf16_t As[64][40];
    __shared__ __attribute__((aligned(16))) bf16_t Bs[64][40];
    const int tid = threadIdx.x;
    const int lane = tid & 63;
    const int wv = tid >> 6;
    const int wm = wv >> 1, wn = wv & 1;
    const int tm = blockIdx.y, tn = blockIdx.x;
    const int l15 = lane & 15, l16 = lane >> 4;

    const int lrow = tid >> 2;
    const int lcol = (tid & 3) * 8;

    int am = tm * 64 + lrow;
    int agrow = (am >> 10) * aBatchStride + aRowOff + (am & 1023);
    const bf16_t* aptr = A + (size_t)agrow * lda + lcol;
    const bf16_t* bptr = Bw + (size_t)(tn * 64 + lrow) * ldb + lcol;

    f32x4v acc[2][2] = {};

    for (int k0 = 0; k0 < K; k0 += 32) {
        bf16x8 av = *reinterpret_cast<const bf16x8*>(aptr + k0);
        bf16x8 bv = *reinterpret_cast<const bf16x8*>(bptr + k0);
        __syncthreads();
        *reinterpret_cast<bf16x8*>(&As[lrow][lcol]) = av;
        *reinterpret_cast<bf16x8*>(&Bs[lrow][lcol]) = bv;
        __syncthreads();
        bf16x8 af[2], bff[2];
#pragma unroll
        for (int i = 0; i < 2; ++i) {
            af[i]  = *reinterpret_cast<const bf16x8*>(&As[wm * 32 + i * 16 + l15][l16 * 8]);
            bff[i] = *reinterpret_cast<const bf16x8*>(&Bs[wn * 32 + i * 16 + l15][l16 * 8]);
        }
#pragma unroll
        for (int mi = 0; mi < 2; ++mi)
#pragma unroll
            for (int ni = 0; ni < 2; ++ni)
                acc[mi][ni] = __builtin_amdgcn_mfma_f32_16x16x32_bf16(af[mi], bff[ni], acc[mi][ni], 0, 0, 0);
    }

#pragma unroll
    for (int mi = 0; mi < 2; ++mi) {
#pragma unroll
        for (int ni = 0; ni < 2; ++ni) {
#pragma unroll
            for (int i = 0; i < 4; ++i) {
                int row = tm * 64 + wm * 32 + mi * 16 + l16 * 4 + i;
                int col = tn * 64 + wn * 32 + ni * 16 + l15;
                float v = acc[mi][ni][i] + bias[col];
                if constexpr (EPI == 0) {
                    ((bf16_t*)Out)[(size_t)row * ldo + outColOff + col] = (bf16_t)v;
                } else if constexpr (EPI == 1) {
                    float g = 0.5f * v * (1.0f + erff(v * 0.70710678118654752f));
                    ((bf16_t*)Out)[(size_t)row * ldo + outColOff + col] = (bf16_t)g;
                } else if constexpr (EPI == 2) {
                    ((float*)Out)[(size_t)row * ldo + col] += gate[row * 5 + gidx] * v;
                } else {
                    ((float*)Out)[(size_t)row * ldo + col] = v;
                }
            }
        }
    }
}

// ---------------------------------------------------------------- attention v2
// qkv: [4096][1536] bf16 (Q | K | V, head-major 64 each)
// MASK: 0 none, 1 rev (keep inside band, direct write), 2 fwd (exclude band)
// SPLITK: 0 direct write to outp; 1 write partials (Op bf16, Mp/Lp f32), kt half per split
template <int MASK, int SPLITK>
__global__ __launch_bounds__(256) void attn2_k(const bf16_t* __restrict__ qkv,
                                               bf16_t* __restrict__ outp,
                                               bf16_t* __restrict__ Op,
                                               float* __restrict__ Mp,
                                               float* __restrict__ Lp) {
    __shared__ __attribute__((aligned(16))) bf16_t Ks[32][72];   // [k][c], pad 8
    __shared__ __attribute__((aligned(16))) bf16_t Vt[64][40];   // [d][k^swz], pad 8
    __shared__ __attribute__((aligned(16))) bf16_t Ps[4][16][40];

    const int tid = threadIdx.x;
    const int lane = tid & 63;
    const int w = tid >> 6;
    const int l15 = lane & 15, l16 = lane >> 4;
    const int qt = blockIdx.x, h = blockIdx.y, z = blockIdx.z;
    int b, split;
    if (SPLITK) { b = z & 3; split = z >> 2; } else { b = z; split = 0; }

    const int qr = qt * 64 + w * 16;      // local q row base
    const int qrow = b * 1024 + qr;       // global token row base
    const int qblk = qr >> 5;
    const int qg = ((w & 1) * 16) + l15;  // q & 31 for this lane's column

    bf16x8 aq[2];
#pragma unroll
    for (int s = 0; s < 2; ++s)
        aq[s] = *reinterpret_cast<const bf16x8*>(
            qkv + (size_t)(qrow + l15) * 1536 + h * 64 + s * 32 + l16 * 8);

    float mrow = -1e30f, lsum = 0.f;   // per-lane, q = l15
    f32x4v accO[4] = {};

    const int srow = tid >> 3, scol8 = (tid & 7) * 8;
    const bf16_t* kvbase = qkv + (size_t)(b * 1024) * 1536 + 512 + h * 64 + scol8;

    int kt0, ktEnd;
    if (SPLITK) { kt0 = split * 16; ktEnd = kt0 + 16; }
    else {
        int qb0 = qt * 2;
        kt0 = qb0 - 3; if (kt0 < 0) kt0 = 0;
        ktEnd = qb0 + 5; if (ktEnd > 32) ktEnd = 32;
    }

    bf16x8 rk, rv, rk2, rv2;
    {
        const bf16_t* p0 = kvbase + (size_t)(kt0 * 32 + srow) * 1536;
        rk = *reinterpret_cast<const bf16x8*>(p0);
        rv = *reinterpret_cast<const bf16x8*>(p0 + 512);
    }

    for (int kt = kt0; kt < ktEnd; ++kt) {
        __syncthreads();
        *reinterpret_cast<bf16x8*>(&Ks[srow][scol8]) = rk;
#pragma unroll
        for (int j = 0; j < 8; ++j) {
            int d = scol8 + j;
            Vt[d][srow ^ ((((d) >> 3) & 3) << 3)] = rv[j];
        }
        if (kt + 1 < ktEnd) {
            const bf16_t* pn = kvbase + (size_t)((kt + 1) * 32 + srow) * 1536;
            rk2 = *reinterpret_cast<const bf16x8*>(pn);
            rv2 = *reinterpret_cast<const bf16x8*>(pn + 512);
        }
        __syncthreads();

        int bd = qblk - kt; if (bd < 0) bd = -bd;
        const bool active = (MASK != 1) || (bd <= 3);
        if (active) {
            bf16x8 k00 = *reinterpret_cast<const bf16x8*>(&Ks[l15][l16 * 8]);
            bf16x8 k01 = *reinterpret_cast<const bf16x8*>(&Ks[l15][32 + l16 * 8]);
            bf16x8 k10 = *reinterpret_cast<const bf16x8*>(&Ks[16 + l15][l16 * 8]);
            bf16x8 k11 = *reinterpret_cast<const bf16x8*>(&Ks[16 + l15][32 + l16 * 8]);
            f32x4v z0 = {}, z1 = {};
            z0 = __builtin_amdgcn_mfma_f32_16x16x32_bf16(k00, aq[0], z0, 0, 0, 0);
            z0 = __builtin_amdgcn_mfma_f32_16x16x32_bf16(k01, aq[1], z0, 0, 0, 0);
            z1 = __builtin_amdgcn_mfma_f32_16x16x32_bf16(k10, aq[0], z1, 0, 0, 0);
            z1 = __builtin_amdgcn_mfma_f32_16x16x32_bf16(k11, aq[1], z1, 0, 0, 0);

            const bool needMask = (MASK == 1) || (MASK == 2 && bd <= 3);
            float p[2][4];
#pragma unroll
            for (int n = 0; n < 2; ++n) {
                f32x4v sv = n ? z1 : z0;
#pragma unroll
                for (int i = 0; i < 4; ++i) {
                    float v = sv[i] * 0.125f;
                    if (needMask) {
                        int k5 = n * 16 + l16 * 4 + i;
                        int dq = qg - k5; if (dq < 0) dq = -dq;
                        bool inside = (dq <= 3);
                        if (MASK == 1 ? !inside : inside) v = -1e30f;
                    }
                    p[n][i] = v;
                }
            }
            // row max over 32 k (8 in-lane + across l16 groups)
            float tmx = p[0][0];
            tmx = fmaxf(tmx, p[0][1]); tmx = fmaxf(tmx, p[0][2]); tmx = fmaxf(tmx, p[0][3]);
            tmx = fmaxf(tmx, p[1][0]); tmx = fmaxf(tmx, p[1][1]);
            tmx = fmaxf(tmx, p[1][2]); tmx = fmaxf(tmx, p[1][3]);
            tmx = fmaxf(tmx, __shfl_xor(tmx, 16, 64));
            tmx = fmaxf(tmx, __shfl_xor(tmx, 32, 64));
            float mn = fmaxf(mrow, tmx);
            float fac = __expf(mrow - mn);
            mrow = mn;
            float rs = 0.f;
#pragma unroll
            for (int n = 0; n < 2; ++n)
#pragma unroll
                for (int i = 0; i < 4; ++i) {
                    p[n][i] = __expf(p[n][i] - mn);
                    rs += p[n][i];
                }
            rs += __shfl_xor(rs, 16, 64);
            rs += __shfl_xor(rs, 32, 64);
            lsum = lsum * fac + rs;

            // broadcast rescale factor to C-layout rows (q = l16*4+i)
            float facq[4];
#pragma unroll
            for (int i = 0; i < 4; ++i) facq[i] = __shfl(fac, l16 * 4 + i, 64);
#pragma unroll
            for (int dblk = 0; dblk < 4; ++dblk)
#pragma unroll
                for (int i = 0; i < 4; ++i) accO[dblk][i] *= facq[i];

            // P -> LDS (wave-private), reread in A-frag layout
#pragma unroll
            for (int n = 0; n < 2; ++n)
#pragma unroll
                for (int i = 0; i < 4; ++i)
                    Ps[w][l15][n * 16 + l16 * 4 + i] = (bf16_t)p[n][i];
            bf16x8 pa = *reinterpret_cast<const bf16x8*>(&Ps[w][l15][l16 * 8]);

#pragma unroll
            for (int dblk = 0; dblk < 4; ++dblk) {
                int d = dblk * 16 + l15;
                bf16x8 bv = *reinterpret_cast<const bf16x8*>(&Vt[d][(l16 ^ ((d >> 3) & 3)) * 8]);
                accO[dblk] = __builtin_amdgcn_mfma_f32_16x16x32_bf16(pa, bv, accO[dblk], 0, 0, 0);
            }
        }
        rk = rk2; rv = rv2;
    }

    if (SPLITK == 0) {
        float inv = 1.0f / lsum;
        float invq[4];
#pragma unroll
        for (int i = 0; i < 4; ++i) invq[i] = __shfl(inv, l16 * 4 + i, 64);
#pragma unroll
        for (int dblk = 0; dblk < 4; ++dblk)
#pragma unroll
            for (int i = 0; i < 4; ++i)
                outp[(size_t)(qrow + l16 * 4 + i) * 512 + h * 64 + dblk * 16 + l15] =
                    (bf16_t)(accO[dblk][i] * invq[i]);
    } else {
        int pb = ((split * 4 + b) * 8 + h) * 1024 + qr;
        if (l16 == 0) { Mp[pb + l15] = mrow; Lp[pb + l15] = lsum; }
#pragma unroll
        for (int dblk = 0; dblk < 4; ++dblk)
#pragma unroll
            for (int i = 0; i < 4; ++i)
                Op[(size_t)(pb + l16 * 4 + i) * 64 + dblk * 16 + l15] = (bf16_t)accO[dblk][i];
    }
}

// ---------------------------------------------------------------- split-K merge
__global__ __launch_bounds__(256) void merge_k(const bf16_t* __restrict__ Op,
                                               const float* __restrict__ Mp,
                                               const float* __restrict__ Lp,
                                               bf16_t* __restrict__ outp) {
    int idx = blockIdx.x * 256 + threadIdx.x;  // 262144 total
    int dg = idx & 7;
    int q = (idx >> 3) & 1023;
    int h = (idx >> 13) & 7;
    int b = idx >> 16;
    int r0 = ((0 * 4 + b) * 8 + h) * 1024 + q;
    int r1 = ((1 * 4 + b) * 8 + h) * 1024 + q;
    float m0 = Mp[r0], m1 = Mp[r1], l0 = Lp[r0], l1 = Lp[r1];
    float M = fmaxf(m0, m1);
    float w0 = __expf(m0 - M), w1 = __expf(m1 - M);
    float den = 1.0f / (l0 * w0 + l1 * w1);
    bf16x8 o0 = *reinterpret_cast<const bf16x8*>(Op + (size_t)r0 * 64 + dg * 8);
    bf16x8 o1 = *reinterpret_cast<const bf16x8*>(Op + (size_t)r1 * 64 + dg * 8);
    bf16x8 o;
#pragma unroll
    for (int j = 0; j < 8; ++j)
        o[j] = (bf16_t)(((float)o0[j] * w0 + (float)o1[j] * w1) * den);
    *reinterpret_cast<bf16x8*>(outp + (size_t)(b * 1024 + q) * 512 + h * 64 + dg * 8) = o;
}

// ---------------------------------------------------------------- LayerNorm (D=512)
__global__ __launch_bounds__(256) void ln_k(const float* __restrict__ in0,
                                            const float* __restrict__ in1,
                                            const float* __restrict__ g,
                                            const float* __restrict__ bb,
                                            float* __restrict__ outf,
                                            bf16_t* __restrict__ outb) {
    __shared__ float red[8];
    int row = blockIdx.x;
    int t = threadIdx.x;
    float x0 = in0[(size_t)row * 512 + t];
    float x1 = in0[(size_t)row * 512 + 256 + t];
    if (in1) {
        x0 += in1[(size_t)row * 512 + t];
        x1 += in1[(size_t)row * 512 + 256 + t];
    }
    float s = x0 + x1, sq = x0 * x0 + x1 * x1;
#pragma unroll
    for (int d = 1; d < 64; d <<= 1) {
        s += __shfl_xor(s, d, 64);
        sq += __shfl_xor(sq, d, 64);
    }
    int w = t >> 6;
    if ((t & 63) == 0) { red[w] = s; red[4 + w] = sq; }
    __syncthreads();
    s = red[0] + red[1] + red[2] + red[3];
    sq = red[4] + red[5] + red[6] + red[7];
    float mean = s * (1.0f / 512.0f);
    float var = sq * (1.0f / 512.0f) - mean * mean;
    float rstd = rsqrtf(var + 1e-5f);
    float y0 = (x0 - mean) * rstd * g[t] + bb[t];
    float y1 = (x1 - mean) * rstd * g[256 + t] + bb[256 + t];
    if (outf) {
        outf[(size_t)row * 512 + t] = y0;
        outf[(size_t)row * 512 + 256 + t] = y1;
    }
    if (outb) {
        outb[(size_t)row * 512 + t] = (bf16_t)y0;
        outb[(size_t)row * 512 + 256 + t] = (bf16_t)y1;
    }
}

// ----------------------------------------------------------------
extern "C" void kernel_launch(void* const* d_in, const int* in_sizes, int n_in,
                              void* d_out, int out_size, void* d_ws, size_t ws_size,
                              hipStream_t stream) {
    (void)in_sizes; (void)n_in; (void)out_size; (void)ws_size;
    const float* x       = (const float*)d_in[0];
    const float* ref_mca = (const float*)d_in[1];
    const float* gate    = (const float*)d_in[2];
    const float *w[5], *wb_bias[5], *ow[5], *ob[5];
    for (int p = 0; p < 5; ++p) {
        w[p]       = (const float*)d_in[3 + p * 4];
        wb_bias[p] = (const float*)d_in[4 + p * 4];
        ow[p]      = (const float*)d_in[5 + p * 4];
        ob[p]      = (const float*)d_in[6 + p * 4];
    }
    const float* ln1_g = (const float*)d_in[23];
    const float* ln1_b = (const float*)d_in[24];
    const float* ln2_g = (const float*)d_in[25];
    const float* ln2_b = (const float*)d_in[26];
    const float* fc1_w = (const float*)d_in[27];
    const float* fc1_b = (const float*)d_in[28];
    const float* fc2_w = (const float*)d_in[29];
    const float* fc2_b = (const float*)d_in[30];

    char* ws = (char*)d_ws;
    size_t off = 0;
    auto alloc = [&](size_t bytes) {
        char* p = ws + off;
        off += (bytes + 255) & ~(size_t)255;
        return p;
    };
    bf16_t* xb   = (bf16_t*)alloc((size_t)4096 * 512 * 2);
    bf16_t* refb = (bf16_t*)alloc((size_t)8192 * 512 * 2);
    bf16_t *wbv[5], *owb[5];
    for (int p = 0; p < 5; ++p) {
        wbv[p] = (bf16_t*)alloc((size_t)1536 * 512 * 2);
        owb[p] = (bf16_t*)alloc((size_t)512 * 512 * 2);
    }
    bf16_t* qkvb = (bf16_t*)alloc((size_t)4096 * 1536 * 2);
    bf16_t* attnout = (bf16_t*)alloc((size_t)4096 * 512 * 2);
    bf16_t* ub = qkvb;  // [4096,2048] aliases qkvb+attnout, dead by MLP time
    float* newx = (float*)alloc((size_t)4096 * 512 * 4);
    float* hbuf = (float*)alloc((size_t)4096 * 512 * 4);
    float* Mpart = (float*)alloc((size_t)2 * 4 * 8 * 1024 * 4);
    float* Lpart = (float*)alloc((size_t)2 * 4 * 8 * 1024 * 4);
    // aliases over dead-by-then regions:
    bf16_t* Opart = (bf16_t*)hbuf;  // 8.39MB == hbuf size; hbuf written only after attns
    bf16_t* hb   = refb;            // refb dead after nsa K-proj
    bf16_t* fc1b = wbv[0];
    bf16_t* fc2b = wbv[1];
    float* ybuf = newx;             // newx consumed by LN1 before G2 writes y

    hipMemsetAsync(newx, 0, (size_t)4096 * 512 * 4, stream);

    auto cvt = [&](const float* src, bf16_t* dst, int n) {
        int n4 = n / 4;
        cvt_k<<<(n4 + 255) / 256, 256, 0, stream>>>(src, dst, n4);
    };
    cvt(x, xb, 4096 * 512);
    cvt(ref_mca, refb, 8192 * 512);
    for (int p = 0; p < 5; ++p) {
        cvt(w[p], wbv[p], 1536 * 512);
        cvt(ow[p], owb[p], 512 * 512);
    }

    dim3 blk(256);
    auto proj = [&](const bf16_t* A, int abs_, int aro, const bf16_t* Wrow,
                    const float* brow, int N, int colOff) {
        dim3 g(N / 64, 64);
        gemm_bt<0><<<g, blk, 0, stream>>>(A, abs_, aro, 512, Wrow, 512, brow,
                                          qkvb, 1536, colOff, nullptr, 0, 4096, N, 512);
    };
    auto attn = [&](int mask) {
        if (mask == 1) {
            attn2_k<1, 0><<<dim3(16, 8, 4), blk, 0, stream>>>(qkvb, attnout, nullptr, nullptr, nullptr);
        } else {
            if (mask == 0)
                attn2_k<0, 1><<<dim3(16, 8, 8), blk, 0, stream>>>(qkvb, nullptr, Opart, Mpart, Lpart);
            else
                attn2_k<2, 1><<<dim3(16, 8, 8), blk, 0, stream>>>(qkvb, nullptr, Opart, Mpart, Lpart);
            merge_k<<<1024, blk, 0, stream>>>(Opart, Mpart, Lpart, attnout);
        }
    };
    auto oproj = [&](int p, int gidx) {
        dim3 g(512 / 64, 64);
        gemm_bt<2><<<g, blk, 0, stream>>>(attnout, 1024, 0, 512, owb[p], 512, ob[p],
                                          newx, 512, 0, gate, gidx, 4096, 512, 512);
    };

    // mca: q from x (once); k,v from each ref chunk; rev mask; gate 0
    proj(xb, 1024, 0, wbv[0], wb_bias[0], 512, 0);
    for (int r = 0; r < 2; ++r) {
        proj(refb, 2048, r * 1024, wbv[0] + (size_t)512 * 512, wb_bias[0] + 512, 1024, 512);
        attn(1);
        oproj(0, 0);
    }
    // ca: q from x; k,v from ref_last; no mask; gate 1
    proj(xb, 1024, 0, wbv[1], wb_bias[1], 512, 0);
    proj(refb, 2048, 1024, wbv[1] + (size_t)512 * 512, wb_bias[1] + 512, 1024, 512);
    attn(0);
    oproj(1, 1);
    // msa: all from x; fwd mask; gate 2
    proj(xb, 1024, 0, wbv[2], wb_bias[2], 1536, 0);
    attn(2);
    oproj(2, 2);
    // nsa: q,v from x; k from ref_last; fwd mask; gate 3
    proj(xb, 1024, 0, wbv[3], wb_bias[3], 512, 0);
    proj(refb, 2048, 1024, wbv[3] + (size_t)512 * 512, wb_bias[3] + 512, 512, 512);
    proj(xb, 1024, 0, wbv[3] + (size_t)1024 * 512, wb_bias[3] + 1024, 512, 1024);
    attn(2);
    oproj(3, 3);
    // sa: all from x; no mask; gate 4
    proj(xb, 1024, 0, wbv[4], wb_bias[4], 1536, 0);
    attn(0);
    oproj(4, 4);

    // weight buffers for MLP now free; convert fc1/fc2 into aliased space
    cvt(fc1_w, fc1b, 2048 * 512);
    cvt(fc2_w, fc2b, 512 * 2048);

    // LN1 -> h (f32 + bf16); hb aliases refb (dead now); hbuf overwrites Opart (dead now)
    ln_k<<<4096, blk, 0, stream>>>(newx, nullptr, ln1_g, ln1_b, hbuf, hb);
    // G1: gelu(h @ fc1^T + b1) -> ub  [4096,2048] bf16
    {
        dim3 g(2048 / 64, 64);
        gemm_bt<1><<<g, blk, 0, stream>>>(hb, 1024, 0, 512, fc1b, 512, fc1_b,
                                          ub, 2048, 0, nullptr, 0, 4096, 2048, 512);
    }
    // G2: ub @ fc2^T + b2 -> y (f32)
    {
        dim3 g(512 / 64, 64);
        gemm_bt<3><<<g, blk, 0, stream>>>(ub, 1024, 0, 2048, fc2b, 2048, fc2_b,
                                          ybuf, 512, 0, nullptr, 0, 4096, 512, 2048);
    }
    // LN2(h + y) -> out: FLOAT32 (reference output dtype is f32)
    ln_k<<<4096, blk, 0, stream>>>(hbuf, ybuf, ln2_g, ln2_b, (float*)d_out, nullptr);
}

// Round 5
// 372.497 us; speedup vs baseline: 1.7143x; 1.2816x over previous
//
#include <hip/hip_runtime.h>

typedef __bf16 bf16_t;
typedef bf16_t bf16x8 __attribute__((ext_vector_type(8)));
typedef float f32x4v __attribute__((ext_vector_type(4)));
typedef unsigned int u32;

__device__ __forceinline__ void gload16(const bf16_t* g, bf16_t* l) {
    __builtin_amdgcn_global_load_lds((const __attribute__((address_space(1))) u32*)g,
                                     (__attribute__((address_space(3))) u32*)l, 16, 0, 0);
}

// ---------------------------------------------------------------- pack f32 -> bf16 (segmented)
struct PackBDesc {
    int nseg;
    int blkOf[21];
    const float* src[20];
    bf16_t* dst[20];
    int chunks[20];
    int dstLd[20];
    int shift[20];
};

__global__ __launch_bounds__(256) void packb_k(PackBDesc d) {
    int b = blockIdx.x;
    int s = 0;
    while (s + 1 < d.nseg && b >= d.blkOf[s + 1]) ++s;
    int idx = (b - d.blkOf[s]) * 256 + threadIdx.x;
    if (idx >= d.chunks[s]) return;
    const float* src = d.src[s] + (size_t)idx * 8;
    int r = idx >> d.shift[s];
    int c8 = idx & ((1 << d.shift[s]) - 1);
    bf16_t* dst = d.dst[s] + (size_t)r * d.dstLd[s] + (size_t)c8 * 8;
    float4 v0 = reinterpret_cast<const float4*>(src)[0];
    float4 v1 = reinterpret_cast<const float4*>(src)[1];
    bf16x8 o;
    o[0] = (bf16_t)v0.x; o[1] = (bf16_t)v0.y; o[2] = (bf16_t)v0.z; o[3] = (bf16_t)v0.w;
    o[4] = (bf16_t)v1.x; o[5] = (bf16_t)v1.y; o[6] = (bf16_t)v1.z; o[7] = (bf16_t)v1.w;
    *reinterpret_cast<bf16x8*>(dst) = o;
}

// ---------------------------------------------------------------- pack f32 -> f32 (linear copies)
struct PackFDesc {
    int nseg;
    int blkOf[15];
    const float* src[14];
    float* dst[14];
    int n[14];
};

__global__ __launch_bounds__(256) void packf_k(PackFDesc d) {
    int b = blockIdx.x;
    int s = 0;
    while (s + 1 < d.nseg && b >= d.blkOf[s + 1]) ++s;
    int idx = (b - d.blkOf[s]) * 256 + threadIdx.x;
    if (idx >= d.n[s]) return;
    d.dst[s][idx] = d.src[s][idx];
}

// ---------------------------------------------------------------- GEMM (m97 structure)
// C[M=4096, N] = A @ B^T + bias. A: [4096 tokens][K] via row remap; B: [N][K] bf16.
// BM=128, BK=32, 256 threads (4 waves, 2x2), BN in {128, 64}.
// EPI: 0 = bf16 store, 1 = gelu->bf16, 3 = f32 store, 4 = f32 + gate*obcat mix
template <int EPI, int BN>
__global__ __launch_bounds__(256) void gemm3(
    const bf16_t* __restrict__ A, int aBS, int aRowOff,
    const bf16_t* __restrict__ B,
    const float* __restrict__ bias,
    void* __restrict__ Out, int ldo,
    const float* __restrict__ gate, const float* __restrict__ obcat,
    int K) {
    constexpr int NB = BN / 32;   // N-frags per wave
    constexpr int WN = BN / 2;
    __shared__ __attribute__((aligned(16))) bf16_t As[128 * 32];
    __shared__ __attribute__((aligned(16))) bf16_t Bs[BN * 32];
    const int tid = threadIdx.x, lane = tid & 63, w = tid >> 6;
    const int wm = w >> 1, wn = w & 1;
    const int l15 = lane & 15, l16 = lane >> 4;
    const int tm = blockIdx.y, tn = blockIdx.x;

    auto remap = [&](int m) { return (m >> 10) * aBS + aRowOff + (m & 1023); };

    // A staging: 8 chunks of 16 rows; wave w stages chunks 2w, 2w+1
    const int colA = (lane & 3) * 8;
    const int rA0 = 32 * w + (lane >> 2);
    const int rA1 = rA0 + 16;
    const bf16_t* aSrc0 = A + (size_t)remap(tm * 128 + rA0) * K + colA;
    const bf16_t* aSrc1 = A + (size_t)remap(tm * 128 + rA1) * K + colA;
    bf16_t* aDst0 = As + (size_t)(2 * w) * 512;
    bf16_t* aDst1 = aDst0 + 512;

    // B staging
    const bf16_t *bSrc0, *bSrc1;
    bf16_t *bDst0, *bDst1;
    if constexpr (BN == 128) {
        bSrc0 = B + (size_t)(tn * 128 + rA0) * K + colA;
        bSrc1 = B + (size_t)(tn * 128 + rA1) * K + colA;
        bDst0 = Bs + (size_t)(2 * w) * 512;
        bDst1 = bDst0 + 512;
    } else {
        bSrc0 = B + (size_t)(tn * 64 + 16 * w + (lane >> 2)) * K + colA;
        bSrc1 = nullptr;
        bDst0 = Bs + (size_t)w * 512;
        bDst1 = nullptr;
    }

    f32x4v acc[4][NB] = {};

    for (int k0 = 0; k0 < K; k0 += 32) {
        gload16(aSrc0, aDst0);
        gload16(aSrc1, aDst1);
        gload16(bSrc0, bDst0);
        if constexpr (BN == 128) gload16(bSrc1, bDst1);
        aSrc0 += 32; aSrc1 += 32; bSrc0 += 32;
        if constexpr (BN == 128) bSrc1 += 32;
        __syncthreads();
        bf16x8 af[4], bff[NB];
#pragma unroll
        for (int mi = 0; mi < 4; ++mi)
            af[mi] = *reinterpret_cast<const bf16x8*>(As + (size_t)(wm * 64 + mi * 16 + l15) * 32 + l16 * 8);
#pragma unroll
        for (int ni = 0; ni < NB; ++ni)
            bff[ni] = *reinterpret_cast<const bf16x8*>(Bs + (size_t)(wn * WN + ni * 16 + l15) * 32 + l16 * 8);
#pragma unroll
        for (int mi = 0; mi < 4; ++mi)
#pragma unroll
            for (int ni = 0; ni < NB; ++ni)
                acc[mi][ni] = __builtin_amdgcn_mfma_f32_16x16x32_bf16(af[mi], bff[ni], acc[mi][ni], 0, 0, 0);
        __syncthreads();
    }

#pragma unroll
    for (int mi = 0; mi < 4; ++mi) {
#pragma unroll
        for (int ni = 0; ni < NB; ++ni) {
#pragma unroll
            for (int i = 0; i < 4; ++i) {
                int row = tm * 128 + wm * 64 + mi * 16 + l16 * 4 + i;
                int n = tn * BN + wn * WN + ni * 16 + l15;
                float v = acc[mi][ni][i];
                if constexpr (EPI != 4) v += bias[n];
                if constexpr (EPI == 0) {
                    ((bf16_t*)Out)[(size_t)row * ldo + n] = (bf16_t)v;
                } else if constexpr (EPI == 1) {
                    float g = 0.5f * v * (1.0f + erff(v * 0.70710678118654752f));
                    ((bf16_t*)Out)[(size_t)row * ldo + n] = (bf16_t)g;
                } else if constexpr (EPI == 3) {
                    ((float*)Out)[(size_t)row * ldo + n] = v;
                } else {
                    // newx = acat @ Wop^T + sum_p gate_p * c_p * ob_p  (mca's ob appears twice)
#pragma unroll
                    for (int p = 0; p < 5; ++p) {
                        float c = (p == 0) ? 2.0f : 1.0f;
                        v += gate[row * 5 + p] * c * obcat[p * 512 + n];
                    }
                    ((float*)Out)[(size_t)row * ldo + n] = v;
                }
            }
        }
    }
}

// ---------------------------------------------------------------- attention
// Q/K/V separate pointers+strides (head-major 64 cols each).
// MASK: 0 none, 1 rev (banded, direct), 2 fwd. SPLITK: 0 direct gated write; 1 gated partials.
template <int MASK, int SPLITK>
__global__ __launch_bounds__(256) void attn3_k(
    const bf16_t* __restrict__ Q, int ldq,
    const bf16_t* __restrict__ Kp, int ldk,
    const bf16_t* __restrict__ Vp, int ldv,
    bf16_t* __restrict__ outCat, int segOff,
    bf16_t* __restrict__ Op, float* __restrict__ Mp, float* __restrict__ Lp,
    const float* __restrict__ gate, int gidx) {
    __shared__ __attribute__((aligned(16))) bf16_t Ks[32][72];
    __shared__ __attribute__((aligned(16))) bf16_t Vt[64][40];
    __shared__ __attribute__((aligned(16))) bf16_t Ps[4][16][40];

    const int tid = threadIdx.x;
    const int lane = tid & 63;
    const int w = tid >> 6;
    const int l15 = lane & 15, l16 = lane >> 4;
    const int qt = blockIdx.x, h = blockIdx.y, z = blockIdx.z;
    int b, split;
    if (SPLITK) { b = z & 3; split = z >> 2; } else { b = z; split = 0; }

    const int qr = qt * 64 + w * 16;
    const int qrow = b * 1024 + qr;
    const int qblk = qr >> 5;
    const int qg = ((w & 1) * 16) + l15;

    bf16x8 aq[2];
#pragma unroll
    for (int s = 0; s < 2; ++s)
        aq[s] = *reinterpret_cast<const bf16x8*>(
            Q + (size_t)(qrow + l15) * ldq + h * 64 + s * 32 + l16 * 8);

    float mrow = -1e30f, lsum = 0.f;
    f32x4v accO[4] = {};

    const int srow = tid >> 3, scol8 = (tid & 7) * 8;
    const bf16_t* kbase = Kp + (size_t)(b * 1024) * ldk + h * 64 + scol8;
    const bf16_t* vbase = Vp + (size_t)(b * 1024) * ldv + h * 64 + scol8;

    int kt0, ktEnd;
    if (SPLITK) { kt0 = split * 16; ktEnd = kt0 + 16; }
    else {
        int qb0 = qt * 2;
        kt0 = qb0 - 3; if (kt0 < 0) kt0 = 0;
        ktEnd = qb0 + 5; if (ktEnd > 32) ktEnd = 32;
    }

    bf16x8 rk, rv, rk2, rv2;
    rk = *reinterpret_cast<const bf16x8*>(kbase + (size_t)(kt0 * 32 + srow) * ldk);
    rv = *reinterpret_cast<const bf16x8*>(vbase + (size_t)(kt0 * 32 + srow) * ldv);

    for (int kt = kt0; kt < ktEnd; ++kt) {
        __syncthreads();
        *reinterpret_cast<bf16x8*>(&Ks[srow][scol8]) = rk;
#pragma unroll
        for (int j = 0; j < 8; ++j) {
            int d = scol8 + j;
            Vt[d][srow ^ (((d >> 3) & 3) << 3)] = rv[j];
        }
        if (kt + 1 < ktEnd) {
            rk2 = *reinterpret_cast<const bf16x8*>(kbase + (size_t)((kt + 1) * 32 + srow) * ldk);
            rv2 = *reinterpret_cast<const bf16x8*>(vbase + (size_t)((kt + 1) * 32 + srow) * ldv);
        }
        __syncthreads();

        int bd = qblk - kt; if (bd < 0) bd = -bd;
        const bool active = (MASK != 1) || (bd <= 3);
        if (active) {
            bf16x8 k00 = *reinterpret_cast<const bf16x8*>(&Ks[l15][l16 * 8]);
            bf16x8 k01 = *reinterpret_cast<const bf16x8*>(&Ks[l15][32 + l16 * 8]);
            bf16x8 k10 = *reinterpret_cast<const bf16x8*>(&Ks[16 + l15][l16 * 8]);
            bf16x8 k11 = *reinterpret_cast<const bf16x8*>(&Ks[16 + l15][32 + l16 * 8]);
            f32x4v z0 = {}, z1 = {};
            z0 = __builtin_amdgcn_mfma_f32_16x16x32_bf16(k00, aq[0], z0, 0, 0, 0);
            z0 = __builtin_amdgcn_mfma_f32_16x16x32_bf16(k01, aq[1], z0, 0, 0, 0);
            z1 = __builtin_amdgcn_mfma_f32_16x16x32_bf16(k10, aq[0], z1, 0, 0, 0);
            z1 = __builtin_amdgcn_mfma_f32_16x16x32_bf16(k11, aq[1], z1, 0, 0, 0);

            const bool needMask = (MASK == 1) || (MASK == 2 && bd <= 3);
            float p[2][4];
#pragma unroll
            for (int n = 0; n < 2; ++n) {
                f32x4v sv = n ? z1 : z0;
#pragma unroll
                for (int i = 0; i < 4; ++i) {
                    float v = sv[i] * 0.125f;
                    if (needMask) {
                        int k5 = n * 16 + l16 * 4 + i;
                        int dq = qg - k5; if (dq < 0) dq = -dq;
                        bool inside = (dq <= 3);
                        if (MASK == 1 ? !inside : inside) v = -1e30f;
                    }
                    p[n][i] = v;
                }
            }
            float tmx = p[0][0];
            tmx = fmaxf(tmx, p[0][1]); tmx = fmaxf(tmx, p[0][2]); tmx = fmaxf(tmx, p[0][3]);
            tmx = fmaxf(tmx, p[1][0]); tmx = fmaxf(tmx, p[1][1]);
            tmx = fmaxf(tmx, p[1][2]); tmx = fmaxf(tmx, p[1][3]);
            tmx = fmaxf(tmx, __shfl_xor(tmx, 16, 64));
            tmx = fmaxf(tmx, __shfl_xor(tmx, 32, 64));
            float mn = fmaxf(mrow, tmx);
            float fac = __expf(mrow - mn);
            mrow = mn;
            float rs = 0.f;
#pragma unroll
            for (int n = 0; n < 2; ++n)
#pragma unroll
                for (int i = 0; i < 4; ++i) {
                    p[n][i] = __expf(p[n][i] - mn);
                    rs += p[n][i];
                }
            rs += __shfl_xor(rs, 16, 64);
            rs += __shfl_xor(rs, 32, 64);
            lsum = lsum * fac + rs;

            float facq[4];
#pragma unroll
            for (int i = 0; i < 4; ++i) facq[i] = __shfl(fac, l16 * 4 + i, 64);
#pragma unroll
            for (int dblk = 0; dblk < 4; ++dblk)
#pragma unroll
                for (int i = 0; i < 4; ++i) accO[dblk][i] *= facq[i];

#pragma unroll
            for (int n = 0; n < 2; ++n)
#pragma unroll
                for (int i = 0; i < 4; ++i)
                    Ps[w][l15][n * 16 + l16 * 4 + i] = (bf16_t)p[n][i];
            bf16x8 pa = *reinterpret_cast<const bf16x8*>(&Ps[w][l15][l16 * 8]);

#pragma unroll
            for (int dblk = 0; dblk < 4; ++dblk) {
                int d = dblk * 16 + l15;
                bf16x8 bv = *reinterpret_cast<const bf16x8*>(&Vt[d][(l16 ^ ((d >> 3) & 3)) * 8]);
                accO[dblk] = __builtin_amdgcn_mfma_f32_16x16x32_bf16(pa, bv, accO[dblk], 0, 0, 0);
            }
        }
        rk = rk2; rv = rv2;
    }

    if (SPLITK == 0) {
        float inv = 1.0f / lsum;
        float invq[4];
#pragma unroll
        for (int i = 0; i < 4; ++i) invq[i] = __shfl(inv, l16 * 4 + i, 64);
#pragma unroll
        for (int dblk = 0; dblk < 4; ++dblk)
#pragma unroll
            for (int i = 0; i < 4; ++i) {
                float g = gate[(size_t)(qrow + l16 * 4 + i) * 5 + gidx];
                outCat[(size_t)(qrow + l16 * 4 + i) * 3072 + segOff + h * 64 + dblk * 16 + l15] =
                    (bf16_t)(accO[dblk][i] * invq[i] * g);
            }
    } else {
        int pb = ((split * 4 + b) * 8 + h) * 1024 + qr;
        if (l16 == 0) { Mp[pb + l15] = mrow; Lp[pb + l15] = lsum; }
#pragma unroll
        for (int dblk = 0; dblk < 4; ++dblk)
#pragma unroll
            for (int i = 0; i < 4; ++i) {
                float g = gate[(size_t)(qrow + l16 * 4 + i) * 5 + gidx];
                Op[(size_t)(pb + l16 * 4 + i) * 64 + dblk * 16 + l15] = (bf16_t)(accO[dblk][i] * g);
            }
    }
}

// ---------------------------------------------------------------- split-K merge
__global__ __launch_bounds__(256) void merge_k(const bf16_t* __restrict__ Op,
                                               const float* __restrict__ Mp,
                                               const float* __restrict__ Lp,
                                               bf16_t* __restrict__ outCat, int segOff) {
    int idx = blockIdx.x * 256 + threadIdx.x;
    int dg = idx & 7;
    int q = (idx >> 3) & 1023;
    int h = (idx >> 13) & 7;
    int b = idx >> 16;
    int r0 = ((0 * 4 + b) * 8 + h) * 1024 + q;
    int r1 = ((1 * 4 + b) * 8 + h) * 1024 + q;
    float m0 = Mp[r0], m1 = Mp[r1], l0 = Lp[r0], l1 = Lp[r1];
    float M = fmaxf(m0, m1);
    float w0 = __expf(m0 - M), w1 = __expf(m1 - M);
    float den = 1.0f / (l0 * w0 + l1 * w1);
    bf16x8 o0 = *reinterpret_cast<const bf16x8*>(Op + (size_t)r0 * 64 + dg * 8);
    bf16x8 o1 = *reinterpret_cast<const bf16x8*>(Op + (size_t)r1 * 64 + dg * 8);
    bf16x8 o;
#pragma unroll
    for (int j = 0; j < 8; ++j)
        o[j] = (bf16_t)(((float)o0[j] * w0 + (float)o1[j] * w1) * den);
    *reinterpret_cast<bf16x8*>(outCat + (size_t)(b * 1024 + q) * 3072 + segOff + h * 64 + dg * 8) = o;
}

// ---------------------------------------------------------------- LayerNorm (D=512)
__global__ __launch_bounds__(256) void ln_k(const float* __restrict__ in0,
                                            const float* __restrict__ in1,
                                            const float* __restrict__ g,
                                            const float* __restrict__ bb,
                                            float* __restrict__ outf,
                                            bf16_t* __restrict__ outb) {
    __shared__ float red[8];
    int row = blockIdx.x;
    int t = threadIdx.x;
    float x0 = in0[(size_t)row * 512 + t];
    float x1 = in0[(size_t)row * 512 + 256 + t];
    if (in1) {
        x0 += in1[(size_t)row * 512 + t];
        x1 += in1[(size_t)row * 512 + 256 + t];
    }
    float s = x0 + x1, sq = x0 * x0 + x1 * x1;
#pragma unroll
    for (int d = 1; d < 64; d <<= 1) {
        s += __shfl_xor(s, d, 64);
        sq += __shfl_xor(sq, d, 64);
    }
    int w = t >> 6;
    if ((t & 63) == 0) { red[w] = s; red[4 + w] = sq; }
    __syncthreads();
    s = red[0] + red[1] + red[2] + red[3];
    sq = red[4] + red[5] + red[6] + red[7];
    float mean = s * (1.0f / 512.0f);
    float var = sq * (1.0f / 512.0f) - mean * mean;
    float rstd = rsqrtf(var + 1e-5f);
    float y0 = (x0 - mean) * rstd * g[t] + bb[t];
    float y1 = (x1 - mean) * rstd * g[256 + t] + bb[256 + t];
    if (outf) {
        outf[(size_t)row * 512 + t] = y0;
        outf[(size_t)row * 512 + 256 + t] = y1;
    }
    if (outb) {
        outb[(size_t)row * 512 + t] = (bf16_t)y0;
        outb[(size_t)row * 512 + 256 + t] = (bf16_t)y1;
    }
}

// ----------------------------------------------------------------
extern "C" void kernel_launch(void* const* d_in, const int* in_sizes, int n_in,
                              void* d_out, int out_size, void* d_ws, size_t ws_size,
                              hipStream_t stream) {
    (void)in_sizes; (void)n_in; (void)out_size; (void)ws_size;
    const float* x       = (const float*)d_in[0];
    const float* ref_mca = (const float*)d_in[1];
    const float* gate    = (const float*)d_in[2];
    const float *w[5], *wb[5], *ow[5], *ob[5];
    for (int p = 0; p < 5; ++p) {
        w[p]  = (const float*)d_in[3 + p * 4];
        wb[p] = (const float*)d_in[4 + p * 4];
        ow[p] = (const float*)d_in[5 + p * 4];
        ob[p] = (const float*)d_in[6 + p * 4];
    }
    const float* ln1_g = (const float*)d_in[23];
    const float* ln1_b = (const float*)d_in[24];
    const float* ln2_g = (const float*)d_in[25];
    const float* ln2_b = (const float*)d_in[26];
    const float* fc1_w = (const float*)d_in[27];
    const float* fc1_b = (const float*)d_in[28];
    const float* fc2_w = (const float*)d_in[29];
    const float* fc2_b = (const float*)d_in[30];

    char* ws = (char*)d_ws;
    size_t off = 0;
    auto alloc = [&](size_t bytes) {
        char* p = ws + off;
        off += (bytes + 255) & ~(size_t)255;
        return p;
    };
    bf16_t* xb    = (bf16_t*)alloc((size_t)4096 * 512 * 2);
    bf16_t* refb  = (bf16_t*)alloc((size_t)8192 * 512 * 2);
    bf16_t* Wxp   = (bf16_t*)alloc((size_t)5120 * 512 * 2);
    bf16_t* WRp   = (bf16_t*)alloc((size_t)2560 * 512 * 2);
    bf16_t* Wop   = (bf16_t*)alloc((size_t)512 * 3072 * 2);
    bf16_t* fc1p  = (bf16_t*)alloc((size_t)2048 * 512 * 2);
    bf16_t* fc2p  = (bf16_t*)alloc((size_t)512 * 2048 * 2);
    float*  bxp   = (float*)alloc((size_t)5120 * 4);
    float*  brp   = (float*)alloc((size_t)2560 * 4);
    float*  obc   = (float*)alloc((size_t)5 * 512 * 4);
    bf16_t* XP    = (bf16_t*)alloc((size_t)4096 * 5120 * 2);
    bf16_t* RP    = (bf16_t*)alloc((size_t)4096 * 2560 * 2);
    bf16_t* R0    = (bf16_t*)alloc((size_t)4096 * 1024 * 2);
    bf16_t* acat  = (bf16_t*)alloc((size_t)4096 * 3072 * 2);
    float*  newx  = (float*)alloc((size_t)4096 * 512 * 4);
    float*  hbuf  = (float*)alloc((size_t)4096 * 512 * 4);
    float*  Mpart = (float*)alloc((size_t)2 * 4 * 8 * 1024 * 4);
    float*  Lpart = (float*)alloc((size_t)2 * 4 * 8 * 1024 * 4);
    // aliases over dead-by-then regions:
    bf16_t* Opart = (bf16_t*)hbuf;  // 8.39MB; hbuf written only at LN1 (after attns)
    bf16_t* hb    = refb;           // refb dead after RP/R0 gemms
    bf16_t* ub    = XP;             // [4096,2048] bf16; XP dead after attns
    float*  ybuf  = newx;           // newx consumed by LN1 before G2 writes

    // ---- pack descriptors
    PackBDesc pb{};
    int nb = 0, blk = 0;
    auto addB = [&](const float* s, bf16_t* dptr, int chunks, int dstLd, int shift) {
        pb.src[nb] = s; pb.dst[nb] = dptr; pb.chunks[nb] = chunks;
        pb.dstLd[nb] = dstLd; pb.shift[nb] = shift;
        pb.blkOf[nb] = blk; blk += (chunks + 255) / 256; ++nb;
    };
    auto addLin = [&](const float* s, bf16_t* dptr, long elems) {
        addB(s, dptr, (int)(elems / 8), 0, 30);
    };
    addLin(x, xb, (long)4096 * 512);
    addLin(ref_mca, refb, (long)8192 * 512);
    addLin(w[0], Wxp, (long)512 * 512);                              // mca wq
    addLin(w[1], Wxp + (size_t)512 * 512, (long)512 * 512);          // ca wq
    addLin(w[2], Wxp + (size_t)1024 * 512, (long)1536 * 512);        // msa wqkv
    addLin(w[3], Wxp + (size_t)2560 * 512, (long)512 * 512);         // nsa wq
    addLin(w[3] + (size_t)1024 * 512, Wxp + (size_t)3072 * 512, (long)512 * 512);  // nsa wv
    addLin(w[4], Wxp + (size_t)3584 * 512, (long)1536 * 512);        // sa wqkv
    addLin(w[0] + (size_t)512 * 512, WRp, (long)1024 * 512);         // mca wk,wv
    addLin(w[1] + (size_t)512 * 512, WRp + (size_t)1024 * 512, (long)1024 * 512);  // ca wk,wv
    addLin(w[3] + (size_t)512 * 512, WRp + (size_t)2048 * 512, (long)512 * 512);   // nsa wk
    // o-weights: acat has 6 segments {mca_r0, mca_r1, ca, msa, nsa, sa} -> ow{0,0,1,2,3,4}
    const float* owSeg[6] = {ow[0], ow[0], ow[1], ow[2], ow[3], ow[4]};
    for (int s = 0; s < 6; ++s)
        addB(owSeg[s], Wop + (size_t)s * 512, 32768, 3072, 6);
    addLin(fc1_w, fc1p, (long)2048 * 512);
    addLin(fc2_w, fc2p, (long)512 * 2048);
    pb.nseg = nb; pb.blkOf[nb] = blk;
    packb_k<<<blk, 256, 0, stream>>>(pb);

    PackFDesc pf{};
    int nf = 0, fblk = 0;
    auto addF = [&](const float* s, float* dptr, int n) {
        pf.src[nf] = s; pf.dst[nf] = dptr; pf.n[nf] = n;
        pf.blkOf[nf] = fblk; fblk += (n + 255) / 256; ++nf;
    };
    addF(wb[0], bxp, 512);
    addF(wb[1], bxp + 512, 512);
    addF(wb[2], bxp + 1024, 1536);
    addF(wb[3], bxp + 2560, 512);
    addF(wb[3] + 1024, bxp + 3072, 512);
    addF(wb[4], bxp + 3584, 1536);
    addF(wb[0] + 512, brp, 1024);
    addF(wb[1] + 512, brp + 1024, 1024);
    addF(wb[3] + 512, brp + 2048, 512);
    for (int p = 0; p < 5; ++p) addF(ob[p], obc + p * 512, 512);
    pf.nseg = nf; pf.blkOf[nf] = fblk;
    packf_k<<<fblk, 256, 0, stream>>>(pf);

    // ---- projections
    gemm3<0, 128><<<dim3(40, 32), 256, 0, stream>>>(xb, 1024, 0, Wxp, bxp, XP, 5120, nullptr, nullptr, 512);
    gemm3<0, 128><<<dim3(20, 32), 256, 0, stream>>>(refb, 2048, 1024, WRp, brp, RP, 2560, nullptr, nullptr, 512);
    gemm3<0, 128><<<dim3(8, 32), 256, 0, stream>>>(refb, 2048, 0, WRp, brp, R0, 1024, nullptr, nullptr, 512);

    // ---- attentions (gated outputs into acat segments)
    // mca r0: banded direct
    attn3_k<1, 0><<<dim3(16, 8, 4), 256, 0, stream>>>(XP, 5120, R0, 1024, R0 + 512, 1024,
                                                      acat, 0, nullptr, nullptr, nullptr, gate, 0);
    // mca r1: banded direct
    attn3_k<1, 0><<<dim3(16, 8, 4), 256, 0, stream>>>(XP, 5120, RP, 2560, RP + 512, 2560,
                                                      acat, 512, nullptr, nullptr, nullptr, gate, 0);
    // ca: splitk
    attn3_k<0, 1><<<dim3(16, 8, 8), 256, 0, stream>>>(XP + 512, 5120, RP + 1024, 2560, RP + 1536, 2560,
                                                      nullptr, 0, Opart, Mpart, Lpart, gate, 1);
    merge_k<<<1024, 256, 0, stream>>>(Opart, Mpart, Lpart, acat, 1024);
    // msa: splitk fwd
    attn3_k<2, 1><<<dim3(16, 8, 8), 256, 0, stream>>>(XP + 1024, 5120, XP + 1536, 5120, XP + 2048, 5120,
                                                      nullptr, 0, Opart, Mpart, Lpart, gate, 2);
    merge_k<<<1024, 256, 0, stream>>>(Opart, Mpart, Lpart, acat, 1536);
    // nsa: splitk fwd (k from ref_last, v from x)
    attn3_k<2, 1><<<dim3(16, 8, 8), 256, 0, stream>>>(XP + 2560, 5120, RP + 2048, 2560, XP + 3072, 5120,
                                                      nullptr, 0, Opart, Mpart, Lpart, gate, 3);
    merge_k<<<1024, 256, 0, stream>>>(Opart, Mpart, Lpart, acat, 2048);
    // sa: splitk
    attn3_k<0, 1><<<dim3(16, 8, 8), 256, 0, stream>>>(XP + 3584, 5120, XP + 4096, 5120, XP + 4608, 5120,
                                                      nullptr, 0, Opart, Mpart, Lpart, gate, 4);
    merge_k<<<1024, 256, 0, stream>>>(Opart, Mpart, Lpart, acat, 2560);

    // ---- fused o-projection: newx = acat @ Wop^T + sum_p gate_p * c_p * ob_p
    gemm3<4, 64><<<dim3(8, 32), 256, 0, stream>>>(acat, 1024, 0, Wop, nullptr, newx, 512, gate, obc, 3072);

    // ---- LN1 -> h
    ln_k<<<4096, 256, 0, stream>>>(newx, nullptr, ln1_g, ln1_b, hbuf, hb);
    // ---- G1: gelu(h @ fc1^T + b1) -> ub
    gemm3<1, 128><<<dim3(16, 32), 256, 0, stream>>>(hb, 1024, 0, fc1p, fc1_b, ub, 2048, nullptr, nullptr, 512);
    // ---- G2: ub @ fc2^T + b2 -> y
    gemm3<3, 64><<<dim3(8, 32), 256, 0, stream>>>(ub, 1024, 0, fc2p, fc2_b, ybuf, 512, nullptr, nullptr, 2048);
    // ---- LN2(h + y) -> out (f32)
    ln_k<<<4096, 256, 0, stream>>>(hbuf, ybuf, ln2_g, ln2_b, (float*)d_out, nullptr);
}